// Round 19
// baseline (495.098 us; speedup 1.0000x reference)
//
#include <hip/hip_runtime.h>
#include <math.h>

#define NPTS 16384
#define WWIN 2048
#define NWIN 7
#define KNB  16
#define CDIM 128
#define NTGT (NPTS - WWIN)   // 14336
#define TPB  4               // targets per nn block (M = 64 rows)
#define NBLK (NTGT / TPB)    // 3584
#define NMAT 12              // 0=pos_w2, 1..5=Wv, 6=wout, 7..11=Mw(=Wq Wk^T)

typedef _Float16 f16;
typedef __attribute__((ext_vector_type(8))) _Float16 f16x8;
typedef __attribute__((ext_vector_type(4))) _Float16 f16x4;
typedef __attribute__((ext_vector_type(2))) _Float16 f16x2;
typedef __attribute__((ext_vector_type(4))) float f32x4;

#define MFMA16(a, b, c)  __builtin_amdgcn_mfma_f32_16x16x32_f16((a), (b), (c), 0, 0, 0)
#define MFMA16H(a, b, c) __builtin_amdgcn_mfma_f32_16x16x16f16((a), (b), (c), 0, 0, 0)

__device__ __forceinline__ unsigned umax_(unsigned a, unsigned b) { return a > b ? a : b; }
__device__ __forceinline__ unsigned umin_(unsigned a, unsigned b) { return a < b ? a : b; }

// ---------------------------------------------------------------------------
// Weight prep -> wt[mat][n][k] f16 (B-operand layout).
//   mat 0 = pos_w2^T, 1..5 = Wv^T, 6 = wout^T, 7..11 = (Wq Wk^T)^T
// ---------------------------------------------------------------------------
__global__ void prep_kernel(const float* __restrict__ pos_w2,
                            const float* __restrict__ wq,
                            const float* __restrict__ wk,
                            const float* __restrict__ wv,
                            const float* __restrict__ wout,
                            f16* __restrict__ wt) {
  const int i = blockIdx.x * 256 + threadIdx.x;
  if (i >= NMAT * 16384) return;
  const int mat = i >> 14;
  const int e   = i & 16383;
  const int k   = e >> 7;
  const int n   = e & 127;
  if (mat < 7) {
    const float* src = (mat == 0) ? pos_w2 : (mat <= 5 ? wv + (mat - 1) * 16384 : wout);
    wt[mat * 16384 + n * 128 + k] = (f16)src[k * 128 + n];
  } else {
    const int l = mat - 7;
    const float* qr = wq + l * 16384 + k * 128;
    const float* kr = wk + l * 16384 + n * 128;
    float sacc = 0.f;
#pragma unroll 4
    for (int c = 0; c < 128; ++c) sacc += qr[c] * kr[c];
    wt[mat * 16384 + n * 128 + k] = (f16)sacc;
  }
}

// ---------------------------------------------------------------------------
// nn helpers
// ---------------------------------------------------------------------------
__device__ __forceinline__ f16x8 ldA(const f16* __restrict__ buf, int row0,
                                     int l15, int lg, int kc) {
  const int row = row0 + l15;
  const int col = (kc * 32 + lg * 8) ^ ((row & 7) << 3);
  return *(const f16x8*)(buf + row * 128 + col);
}

__device__ __forceinline__ void stD(f16* __restrict__ buf, int row0, int col0,
                                    int l15, int lg, const f32x4 v) {
#pragma unroll
  for (int r = 0; r < 4; ++r) {
    const int row = row0 + lg * 4 + r;
    const int col = (col0 + l15) ^ ((row & 7) << 3);
    buf[row * 128 + col] = (f16)v[r];
  }
}

// Half-gemm: one 16-col block (acc[4] = 16 regs live).
__device__ __forceinline__ void gemm_half(const f16* __restrict__ src,
                                          const f16* __restrict__ wmat,
                                          int l15, int lg, int ncol,
                                          f32x4 (&acc)[4]) {
#pragma unroll
  for (int kc = 0; kc < 4; ++kc) {
    const f16x8 b = *(const f16x8*)(wmat + (ncol + l15) * 128 + kc * 32 + lg * 8);
#pragma unroll
    for (int mt = 0; mt < 4; ++mt) {
      const f16x8 a = ldA(src, mt * 16, l15, lg, kc);
      acc[mt] = MFMA16(a, b, acc[mt]);
    }
  }
}

// ---------------------------------------------------------------------------
// Fused kernel. 2 barriers/layer; NOTHING register-resident crosses a
// barrier (spill-free at the (256,3) budget).
// Layer: P1 {G = f@Mw -> qA, col-sliced} BAR
//        P2 {own-target: S (A=G_own, B=own f A-frags) -> softmax -> pAh own
//            slice -> per 16-col block: V-gemm (A=own f frags) -> D-frag ==
//            PV B-frag -> PV MFMA16H (C from fA) -> stD own rows} BAR
// ---------------------------------------------------------------------------
__global__ __launch_bounds__(256, 3)
void nn_kernel(
    const float4* __restrict__ bx, const f16* __restrict__ wt,
    const float* __restrict__ attr_w, const float* __restrict__ attr_b,
    const float* __restrict__ pos_w1, const float* __restrict__ pos_b1,
    const float* __restrict__ pos_b2, const float* __restrict__ bout,
    const float* __restrict__ ms_w1, const float* __restrict__ ms_b1,
    const float* __restrict__ ms_w2, const float* __restrict__ ms_b2,
    const float* __restrict__ ms_w3, const float* __restrict__ ms_b3,
    float* __restrict__ partials) {
  __shared__ __align__(16) f16 fA[64 * 128];    // 16KB  f (A-layout, swizzled)
  __shared__ __align__(16) f16 qA[64 * 128];    // 16KB  pos1 / G
  __shared__ __align__(16) char aux[4096];      // 4KB   nbr/ggs -> P[4][16][16] -> epi

  const int t     = threadIdx.x;
  const int wv    = t >> 6;
  const int lane  = t & 63;
  const int l15   = lane & 15;
  const int lg    = lane >> 4;
  const int n0    = wv * 32;
  const int slot0 = (NBLK - 1 - blockIdx.x) * TPB;   // heavy windows first

  f16* pAh = (f16*)aux;                    // [4][16][16] P (m-major)
  unsigned* nbr = (unsigned*)aux;          // [64] (dead before pAh use)
  float* ggs = (float*)(aux + 1024);       // [64][4] (dead before pAh use)

  // ================= KNN prologue: 4-deep prefetch ring =================
  {
    const int  slot = slot0 + wv;
    const int  cur  = WWIN * ((slot0 >> 11) + 1);    // multiple of 2048
    const float4 tp = bx[WWIN + slot];

    // sorted ascending: u0 <= u1 <= u2 <= u3
    unsigned u0 = 0xFFFFFFF0u, u1 = 0xFFFFFFF1u, u2 = 0xFFFFFFF2u, u3 = 0xFFFFFFF3u;

#define INS4(P) { const unsigned p_ = (P);                                     \
    const unsigned t0 = umax_(u0, p_); u0 = umin_(u0, p_);                     \
    const unsigned t1 = umax_(u1, t0); u1 = umin_(u1, t0);                     \
    const unsigned t2 = umax_(u2, t1); u2 = umin_(u2, t1);                     \
    u3 = umin_(u3, t2); }
#define PROC(CA, CB, JJ) {                                                     \
    const float dx0 = tp.x - (CA).x, dy0 = tp.y - (CA).y, dz0 = tp.z - (CA).z; \
    const float dx1 = tp.x - (CB).x, dy1 = tp.y - (CB).y, dz1 = tp.z - (CB).z; \
    const float d20 = dx0 * dx0 + dy0 * dy0 + dz0 * dz0;                       \
    const float d21 = dx1 * dx1 + dy1 * dy1 + dz1 * dz1;                       \
    const unsigned p0 = ((__float_as_uint(d20) << 1) & 0xFFFFC000u) | (unsigned)(JJ);      \
    const unsigned p1 = ((__float_as_uint(d21) << 1) & 0xFFFFC000u) | (unsigned)((JJ) + 64); \
    INS4(p0) INS4(p1) }

    float4 a0 = bx[lane],       b0 = bx[lane + 64];
    float4 a1 = bx[lane + 128], b1 = bx[lane + 192];
    float4 a2 = bx[lane + 256], b2 = bx[lane + 320];
    float4 a3 = bx[lane + 384], b3 = bx[lane + 448];
    for (int j = lane; j < cur; j += 512) {   // cur % 512 == 0
      const float4 n0_ = bx[j + 512], n1_ = bx[j + 576];
      const float4 n2_ = bx[j + 640], n3_ = bx[j + 704];
      const float4 n4_ = bx[j + 768], n5_ = bx[j + 832];
      const float4 n6_ = bx[j + 896], n7_ = bx[j + 960];   // max idx < 16384
      PROC(a0, b0, j)       a0 = n0_; b0 = n1_;
      PROC(a1, b1, j + 128) a1 = n2_; b1 = n3_;
      PROC(a2, b2, j + 256) a2 = n4_; b2 = n5_;
      PROC(a3, b3, j + 384) a3 = n6_; b3 = n7_;
    }
#undef PROC
#undef INS4

    // wave-wide 16x extract-min over sorted heads (exact merge)
    for (int n = 0; n < 16; ++n) {
      unsigned m = u0;
      m = umin_(m, (unsigned)__shfl_xor((int)m, 1));
      m = umin_(m, (unsigned)__shfl_xor((int)m, 2));
      m = umin_(m, (unsigned)__shfl_xor((int)m, 4));
      m = umin_(m, (unsigned)__shfl_xor((int)m, 8));
      m = umin_(m, (unsigned)__shfl_xor((int)m, 16));
      m = umin_(m, (unsigned)__shfl_xor((int)m, 32));
      if (lane == n) nbr[wv * 16 + n] = m & 0x3FFFu;
      if (u0 == m) { u0 = u1; u1 = u2; u2 = u3; u3 = 0xFFFFFFFFu; }
    }
  }
  __syncthreads();

  // ================= gather + center + max-norm =================
  if (t < 64) {
    const int nid  = (int)nbr[t];
    const float4 p = bx[nid];
    float sx = p.x, sy = p.y, sz = p.z;
#pragma unroll
    for (int m = 1; m < 16; m <<= 1) {
      sx += __shfl_xor(sx, m); sy += __shfl_xor(sy, m); sz += __shfl_xor(sz, m);
    }
    const float gx = p.x - sx * 0.0625f;
    const float gy = p.y - sy * 0.0625f;
    const float gz = p.z - sz * 0.0625f;
    float nr = sqrtf(gx * gx + gy * gy + gz * gz);
#pragma unroll
    for (int m = 1; m < 16; m <<= 1) nr = fmaxf(nr, __shfl_xor(nr, m));
    const float inv = 1.f / fmaxf(nr, 1e-8f);
    ggs[t * 4 + 0] = gx * inv; ggs[t * 4 + 1] = gy * inv;
    ggs[t * 4 + 2] = gz * inv; ggs[t * 4 + 3] = p.w;
  }
  __syncthreads();

  // ---- pos1 = relu(gg @ pos_w1 + b1) -> qA (A-layout f16, swizzled) ----
  {
    const int row = t & 63;
    const int cb  = (t >> 6) * 32;
    const float gx = ggs[row * 4], gy = ggs[row * 4 + 1], gz = ggs[row * 4 + 2];
#pragma unroll
    for (int c = cb; c < cb + 32; c += 2) {
      const float h0 = pos_b1[c]     + gx * pos_w1[c]     + gy * pos_w1[128 + c]     + gz * pos_w1[256 + c];
      const float h1 = pos_b1[c + 1] + gx * pos_w1[c + 1] + gy * pos_w1[128 + c + 1] + gz * pos_w1[256 + c + 1];
      f16x2 pr; pr[0] = (f16)fmaxf(h0, 0.f); pr[1] = (f16)fmaxf(h1, 0.f);
      *(f16x2*)(qA + row * 128 + (c ^ ((row & 7) << 3))) = pr;
    }
  }
  __syncthreads();

  // ---- f0 = pos1 @ pos_w2^T + b2 + ga*attr_w + attr_b -> fA ----
  {
#pragma unroll
    for (int nt = 0; nt < 2; ++nt) {
      f32x4 acc[4];
#pragma unroll
      for (int mt = 0; mt < 4; ++mt) acc[mt] = (f32x4){0.f, 0.f, 0.f, 0.f};
      gemm_half(qA, wt, l15, lg, n0 + nt * 16, acc);
      const int col = n0 + nt * 16 + l15;
      const float bias = pos_b2[col] + attr_b[col];
      const float aw   = attr_w[col];
#pragma unroll
      for (int mt = 0; mt < 4; ++mt) {
#pragma unroll
        for (int r = 0; r < 4; ++r)
          acc[mt][r] += bias + ggs[(mt * 16 + lg * 4 + r) * 4 + 3] * aw;
        stD(fA, mt * 16, n0 + nt * 16, l15, lg, acc[mt]);
      }
    }
  }
  __syncthreads();

  // ---- 5 attention layers, 2 barriers each ----
  for (int l = 0; l < 5; ++l) {
    {  // P1: G = f @ Mw -> qA (col-sliced, 2 half-passes)
#pragma unroll
      for (int nt = 0; nt < 2; ++nt) {
        f32x4 acc[4];
#pragma unroll
        for (int mt = 0; mt < 4; ++mt) acc[mt] = (f32x4){0.f, 0.f, 0.f, 0.f};
        gemm_half(fA, wt + (7 + l) * 16384, l15, lg, n0 + nt * 16, acc);
#pragma unroll
        for (int mt = 0; mt < 4; ++mt)
          stD(qA, mt * 16, n0 + nt * 16, l15, lg, acc[mt]);
      }
    }
    __syncthreads();
    {  // P2: own-target S -> softmax -> V+PV (all intra-wave)
      // hoisted own f A-frags: S's B-operand AND V's A-operand
      f16x8 af[4];
#pragma unroll
      for (int kc = 0; kc < 4; ++kc) af[kc] = ldA(fA, wv * 16, l15, lg, kc);
      // S = G_own @ f_own^T (K=32)
      f32x4 s = (f32x4){0.f, 0.f, 0.f, 0.f};
#pragma unroll
      for (int kc = 0; kc < 4; ++kc)
        s = MFMA16(ldA(qA, wv * 16, l15, lg, kc), af[kc], s);
#pragma unroll
      for (int r = 0; r < 4; ++r) {
        float v = s[r] * 0.08838834764831844055f;   // 1/sqrt(128)
        float mx = v;
#pragma unroll
        for (int m = 1; m < 16; m <<= 1) mx = fmaxf(mx, __shfl_xor(mx, m));
        const float e = __expf(v - mx);
        float sm = e;
#pragma unroll
        for (int m = 1; m < 16; m <<= 1) sm += __shfl_xor(sm, m);
        pAh[wv * 256 + (lg * 4 + r) * 16 + l15] = (f16)(e / sm);   // P[m][k]
      }
      const f16x4 aP = *(const f16x4*)(pAh + wv * 256 + l15 * 16 + lg * 4);
      // V own-rows + PV, per 16-col block (transient regs only)
      const f16* wvm = wt + (1 + l) * 16384;
#pragma unroll
      for (int nt = 0; nt < 8; ++nt) {
        f32x4 vacc = (f32x4){0.f, 0.f, 0.f, 0.f};
#pragma unroll
        for (int kc = 0; kc < 4; ++kc) {
          const f16x8 b = *(const f16x8*)(wvm + (nt * 16 + l15) * 128 + kc * 32 + lg * 8);
          vacc = MFMA16(af[kc], b, vacc);
        }
        f16x4 vf;
#pragma unroll
        for (int r = 0; r < 4; ++r) vf[r] = (f16)vacc[r];
        f32x4 c;
#pragma unroll
        for (int r = 0; r < 4; ++r) {
          const int row = wv * 16 + lg * 4 + r;
          const int col = (nt * 16 + l15) ^ ((row & 7) << 3);
          c[r] = (float)fA[row * 128 + col];
        }
        c = MFMA16H(aP, vf, c);
        stD(fA, wv * 16, nt * 16, l15, lg, c);
      }
    }
    __syncthreads();
  }

  // ---- feature head (epilogue overlays aux) ----
  float* feats = (float*)aux;          // [4][128] f32 (2048B)
  float* h1s   = feats + 512;          // [4][64]  (1024B)
  float* h2s   = h1s + 256;            // [4][16]  (256B)
  float* btmp  = h2s + 64;             // [4]
  {
#pragma unroll
    for (int nt = 0; nt < 2; ++nt) {
      f32x4 acc[4];
#pragma unroll
      for (int mt = 0; mt < 4; ++mt) acc[mt] = (f32x4){0.f, 0.f, 0.f, 0.f};
      gemm_half(fA, wt + 6 * 16384, l15, lg, n0 + nt * 16, acc);
      const int col = n0 + nt * 16 + l15;
      const float bo = bout[col];
#pragma unroll
      for (int mt = 0; mt < 4; ++mt) {
        const f32x4 v = acc[mt];
        float m = fmaxf(fmaxf(v[0], v[1]), fmaxf(v[2], v[3])) + bo;
        m = fmaxf(m, __shfl_xor(m, 16));
        m = fmaxf(m, __shfl_xor(m, 32));
        if (lg == 0) feats[mt * 128 + col] = m;
      }
    }
  }
  __syncthreads();
  {  // h1 = relu(feat @ ms_w1 + b1): 4 targets x 64
    const int tt = t >> 6, h = t & 63;
    float a = ms_b1[h];
#pragma unroll 4
    for (int c = 0; c < 128; ++c) a += feats[tt * 128 + c] * ms_w1[c * 64 + h];
    h1s[tt * 64 + h] = fmaxf(a, 0.f);
  }
  __syncthreads();
  if (t < 64) {
    const int tt = t >> 4, h = t & 15;
    float a = ms_b2[h];
#pragma unroll 4
    for (int c = 0; c < 64; ++c) a += h1s[tt * 64 + c] * ms_w2[c * 16 + h];
    h2s[tt * 16 + h] = fmaxf(a, 0.f);
  }
  __syncthreads();
  if (t < TPB) {
    float mu = ms_b3[0], lgs = ms_b3[1];
#pragma unroll
    for (int c = 0; c < 16; ++c) {
      mu  += h2s[t * 16 + c] * ms_w3[2 * c];
      lgs += h2s[t * 16 + c] * ms_w3[2 * c + 1];
    }
    const float sigma = expf(lgs);
    const float inv   = 1.f / (sigma * 1.41421356237309504880f);
    const float ta    = ((const float*)bx)[(WWIN + slot0 + t) * 4 + 3];
    const float p = 0.5f * (erff((ta + 0.5f - mu) * inv) - erff((ta - 0.5f - mu) * inv));
    float bits = -log2f(p + 1e-10f);
    btmp[t] = fminf(fmaxf(bits, 0.f), 50.f);
  }
  __syncthreads();
  if (t == 0) partials[blockIdx.x] = btmp[0] + btmp[1] + btmp[2] + btmp[3];
}

// ---------------------------------------------------------------------------
__global__ void reduce_kernel(const float* __restrict__ partials, float* __restrict__ out) {
  float s = 0.f;
  for (int i = threadIdx.x; i < NBLK; i += 256) s += partials[i];
#pragma unroll
  for (int m = 1; m < 64; m <<= 1) s += __shfl_xor(s, m);
  __shared__ float wsum[4];
  if ((threadIdx.x & 63) == 0) wsum[threadIdx.x >> 6] = s;
  __syncthreads();
  if (threadIdx.x == 0) out[0] = wsum[0] + wsum[1] + wsum[2] + wsum[3];
}

// ---------------------------------------------------------------------------
extern "C" void kernel_launch(void* const* d_in, const int* in_sizes, int n_in,
                              void* d_out, int out_size, void* d_ws, size_t ws_size,
                              hipStream_t stream) {
  const float4* bx     = (const float4*)d_in[0];
  const float* attr_w  = (const float*)d_in[1];
  const float* attr_b  = (const float*)d_in[2];
  const float* pos_w1  = (const float*)d_in[3];
  const float* pos_b1  = (const float*)d_in[4];
  const float* pos_w2  = (const float*)d_in[5];
  const float* pos_b2  = (const float*)d_in[6];
  const float* wq      = (const float*)d_in[7];
  const float* wk      = (const float*)d_in[8];
  const float* wv      = (const float*)d_in[9];
  const float* wout    = (const float*)d_in[10];
  const float* bout    = (const float*)d_in[11];
  const float* ms_w1   = (const float*)d_in[12];
  const float* ms_b1   = (const float*)d_in[13];
  const float* ms_w2   = (const float*)d_in[14];
  const float* ms_b2   = (const float*)d_in[15];
  const float* ms_w3   = (const float*)d_in[16];
  const float* ms_b3   = (const float*)d_in[17];

  f16*   wt       = (f16*)((char*)d_ws);                 // 384KB @ 0
  float* partials = (float*)((char*)d_ws + (1u << 19));  // 14KB  @ 512KB

  prep_kernel<<<(NMAT * 16384 + 255) / 256, 256, 0, stream>>>(pos_w2, wq, wk, wv, wout, wt);
  nn_kernel<<<NBLK, 256, 0, stream>>>(bx, wt, attr_w, attr_b,
                                      pos_w1, pos_b1, pos_b2, bout,
                                      ms_w1, ms_b1, ms_w2, ms_b2, ms_w3, ms_b3,
                                      partials);
  reduce_kernel<<<1, 256, 0, stream>>>(partials, (float*)d_out);
}

// Round 20
// 361.544 us; speedup vs baseline: 1.3694x; 1.3694x over previous
//
#include <hip/hip_runtime.h>
#include <math.h>

#define NPTS 16384
#define WWIN 2048
#define NWIN 7
#define KNB  16
#define CDIM 128
#define NTGT (NPTS - WWIN)   // 14336
#define TPB  4               // targets per nn block (M = 64 rows)
#define NBLK (NTGT / TPB)    // 3584
#define NMAT 12              // 0=pos_w2, 1..5=Wv, 6=wout, 7..11=Mw(=Wq Wk^T)

typedef _Float16 f16;
typedef __attribute__((ext_vector_type(8))) _Float16 f16x8;
typedef __attribute__((ext_vector_type(4))) _Float16 f16x4;
typedef __attribute__((ext_vector_type(2))) _Float16 f16x2;
typedef __attribute__((ext_vector_type(4))) float f32x4;

#define MFMA16(a, b, c)  __builtin_amdgcn_mfma_f32_16x16x32_f16((a), (b), (c), 0, 0, 0)
#define MFMA16H(a, b, c) __builtin_amdgcn_mfma_f32_16x16x16f16((a), (b), (c), 0, 0, 0)

__device__ __forceinline__ unsigned umax_(unsigned a, unsigned b) { return a > b ? a : b; }
__device__ __forceinline__ unsigned umin_(unsigned a, unsigned b) { return a < b ? a : b; }

// ---------------------------------------------------------------------------
// Weight prep -> wt[mat][n][k] f16 (B-operand layout).
//   mat 0 = pos_w2^T, 1..5 = Wv^T, 6 = wout^T, 7..11 = (Wq Wk^T)^T
// ---------------------------------------------------------------------------
__global__ void prep_kernel(const float* __restrict__ pos_w2,
                            const float* __restrict__ wq,
                            const float* __restrict__ wk,
                            const float* __restrict__ wv,
                            const float* __restrict__ wout,
                            f16* __restrict__ wt) {
  const int i = blockIdx.x * 256 + threadIdx.x;
  if (i >= NMAT * 16384) return;
  const int mat = i >> 14;
  const int e   = i & 16383;
  const int k   = e >> 7;
  const int n   = e & 127;
  if (mat < 7) {
    const float* src = (mat == 0) ? pos_w2 : (mat <= 5 ? wv + (mat - 1) * 16384 : wout);
    wt[mat * 16384 + n * 128 + k] = (f16)src[k * 128 + n];
  } else {
    const int l = mat - 7;
    const float* qr = wq + l * 16384 + k * 128;
    const float* kr = wk + l * 16384 + n * 128;
    float sacc = 0.f;
#pragma unroll 4
    for (int c = 0; c < 128; ++c) sacc += qr[c] * kr[c];
    wt[mat * 16384 + n * 128 + k] = (f16)sacc;
  }
}

// ---------------------------------------------------------------------------
// nn helpers
// ---------------------------------------------------------------------------
__device__ __forceinline__ f16x8 ldA(const f16* __restrict__ buf, int row0,
                                     int l15, int lg, int kc) {
  const int row = row0 + l15;
  const int col = (kc * 32 + lg * 8) ^ ((row & 7) << 3);
  return *(const f16x8*)(buf + row * 128 + col);
}

__device__ __forceinline__ void stD(f16* __restrict__ buf, int row0, int col0,
                                    int l15, int lg, const f32x4 v) {
#pragma unroll
  for (int r = 0; r < 4; ++r) {
    const int row = row0 + lg * 4 + r;
    const int col = (col0 + l15) ^ ((row & 7) << 3);
    buf[row * 128 + col] = (f16)v[r];
  }
}

__device__ __forceinline__ void zacc(f32x4 (&acc)[4][2]) {
#pragma unroll
  for (int mt = 0; mt < 4; ++mt)
#pragma unroll
    for (int nt = 0; nt < 2; ++nt) acc[mt][nt] = (f32x4){0.f, 0.f, 0.f, 0.f};
}

__device__ __forceinline__ void gemm_tile(const f16* __restrict__ src,
                                          const f16* __restrict__ wmat,
                                          int l15, int lg, int n0,
                                          f32x4 (&acc)[4][2]) {
#pragma unroll
  for (int kc = 0; kc < 4; ++kc) {
    const f16x8 b0 = *(const f16x8*)(wmat + (n0 + l15) * 128 + kc * 32 + lg * 8);
    const f16x8 b1 = *(const f16x8*)(wmat + (n0 + 16 + l15) * 128 + kc * 32 + lg * 8);
#pragma unroll
    for (int mt = 0; mt < 4; ++mt) {
      const f16x8 a = ldA(src, mt * 16, l15, lg, kc);
      acc[mt][0] = MFMA16(a, b0, acc[mt][0]);
      acc[mt][1] = MFMA16(a, b1, acc[mt][1]);
    }
  }
}

// ---------------------------------------------------------------------------
// Fused kernel (R15 best config, 362 us). 4 targets/block, 256 thr = 4 waves.
// LDS = fA+qA+aux = 36KB. Persistent col-sliced facc[4][2].
// Layer (3 barriers):
//   P1 {G = f@Mw -> qA (col-sliced); V = f@Wv -> regs; vfrag = f16x4(Vacc)}
//   bar
//   P2 {S = G_own @ f_own^T (K=32); softmax -> pAh[wv][16][16]}
//   bar
//   P3 {PV: facc[tt][nt] = mfma_16x16x16(P_tt, vfrag[tt][nt], facc); stD fA}
//   bar
// KEY: V-gemm D-frag (rows tt*16+lg*4+r, col n0+nt*16+l15) IS the K=16 PV
// B-frag (k=lg*4+j, n=l15) -- zero data movement, no vtB buffer.
// ---------------------------------------------------------------------------
__global__ __launch_bounds__(256, 2)
void nn_kernel(
    const float4* __restrict__ bx, const f16* __restrict__ wt,
    const float* __restrict__ attr_w, const float* __restrict__ attr_b,
    const float* __restrict__ pos_w1, const float* __restrict__ pos_b1,
    const float* __restrict__ pos_b2, const float* __restrict__ bout,
    const float* __restrict__ ms_w1, const float* __restrict__ ms_b1,
    const float* __restrict__ ms_w2, const float* __restrict__ ms_b2,
    const float* __restrict__ ms_w3, const float* __restrict__ ms_b3,
    float* __restrict__ partials) {
  __shared__ __align__(16) f16 fA[64 * 128];    // 16KB  f (A-layout, swizzled)
  __shared__ __align__(16) f16 qA[64 * 128];    // 16KB  pos1 / G
  __shared__ __align__(16) char aux[4096];      // 4KB   nbr/ggs -> P[4][16][16] -> epi

  const int t     = threadIdx.x;
  const int wv    = t >> 6;
  const int lane  = t & 63;
  const int l15   = lane & 15;
  const int lg    = lane >> 4;
  const int n0    = wv * 32;
  const int slot0 = (NBLK - 1 - blockIdx.x) * TPB;   // heavy windows first

  f16* pAh = (f16*)aux;                    // [4][16][16] P (m-major)
  unsigned* nbr = (unsigned*)aux;          // [64] (dead before pAh use)
  float* ggs = (float*)(aux + 1024);       // [64][4] (dead before pAh use)

  // ================= KNN prologue: 4-deep prefetch ring =================
  {
    const int  slot = slot0 + wv;
    const int  cur  = WWIN * ((slot0 >> 11) + 1);    // multiple of 2048
    const float4 tp = bx[WWIN + slot];

    // sorted ascending: u0 <= u1 <= u2 <= u3
    unsigned u0 = 0xFFFFFFF0u, u1 = 0xFFFFFFF1u, u2 = 0xFFFFFFF2u, u3 = 0xFFFFFFF3u;

#define INS4(P) { const unsigned p_ = (P);                                     \
    const unsigned t0 = umax_(u0, p_); u0 = umin_(u0, p_);                     \
    const unsigned t1 = umax_(u1, t0); u1 = umin_(u1, t0);                     \
    const unsigned t2 = umax_(u2, t1); u2 = umin_(u2, t1);                     \
    u3 = umin_(u3, t2); }
#define PROC(CA, CB, JJ) {                                                     \
    const float dx0 = tp.x - (CA).x, dy0 = tp.y - (CA).y, dz0 = tp.z - (CA).z; \
    const float dx1 = tp.x - (CB).x, dy1 = tp.y - (CB).y, dz1 = tp.z - (CB).z; \
    const float d20 = dx0 * dx0 + dy0 * dy0 + dz0 * dz0;                       \
    const float d21 = dx1 * dx1 + dy1 * dy1 + dz1 * dz1;                       \
    const unsigned p0 = ((__float_as_uint(d20) << 1) & 0xFFFFC000u) | (unsigned)(JJ);      \
    const unsigned p1 = ((__float_as_uint(d21) << 1) & 0xFFFFC000u) | (unsigned)((JJ) + 64); \
    INS4(p0) INS4(p1) }

    float4 a0 = bx[lane],       b0 = bx[lane + 64];
    float4 a1 = bx[lane + 128], b1 = bx[lane + 192];
    float4 a2 = bx[lane + 256], b2 = bx[lane + 320];
    float4 a3 = bx[lane + 384], b3 = bx[lane + 448];
    for (int j = lane; j < cur; j += 512) {   // cur % 512 == 0
      const float4 n0_ = bx[j + 512], n1_ = bx[j + 576];
      const float4 n2_ = bx[j + 640], n3_ = bx[j + 704];
      const float4 n4_ = bx[j + 768], n5_ = bx[j + 832];
      const float4 n6_ = bx[j + 896], n7_ = bx[j + 960];   // max idx < 16384
      PROC(a0, b0, j)       a0 = n0_; b0 = n1_;
      PROC(a1, b1, j + 128) a1 = n2_; b1 = n3_;
      PROC(a2, b2, j + 256) a2 = n4_; b2 = n5_;
      PROC(a3, b3, j + 384) a3 = n6_; b3 = n7_;
    }
#undef PROC
#undef INS4

    // wave-wide 16x extract-min over sorted heads (exact merge)
    for (int n = 0; n < 16; ++n) {
      unsigned m = u0;
      m = umin_(m, (unsigned)__shfl_xor((int)m, 1));
      m = umin_(m, (unsigned)__shfl_xor((int)m, 2));
      m = umin_(m, (unsigned)__shfl_xor((int)m, 4));
      m = umin_(m, (unsigned)__shfl_xor((int)m, 8));
      m = umin_(m, (unsigned)__shfl_xor((int)m, 16));
      m = umin_(m, (unsigned)__shfl_xor((int)m, 32));
      if (lane == n) nbr[wv * 16 + n] = m & 0x3FFFu;
      if (u0 == m) { u0 = u1; u1 = u2; u2 = u3; u3 = 0xFFFFFFFFu; }
    }
  }
  __syncthreads();

  // ================= gather + center + max-norm =================
  if (t < 64) {
    const int nid  = (int)nbr[t];
    const float4 p = bx[nid];
    float sx = p.x, sy = p.y, sz = p.z;
#pragma unroll
    for (int m = 1; m < 16; m <<= 1) {
      sx += __shfl_xor(sx, m); sy += __shfl_xor(sy, m); sz += __shfl_xor(sz, m);
    }
    const float gx = p.x - sx * 0.0625f;
    const float gy = p.y - sy * 0.0625f;
    const float gz = p.z - sz * 0.0625f;
    float nr = sqrtf(gx * gx + gy * gy + gz * gz);
#pragma unroll
    for (int m = 1; m < 16; m <<= 1) nr = fmaxf(nr, __shfl_xor(nr, m));
    const float inv = 1.f / fmaxf(nr, 1e-8f);
    ggs[t * 4 + 0] = gx * inv; ggs[t * 4 + 1] = gy * inv;
    ggs[t * 4 + 2] = gz * inv; ggs[t * 4 + 3] = p.w;
  }
  __syncthreads();

  // ---- pos1 = relu(gg @ pos_w1 + b1) -> qA (A-layout f16, swizzled) ----
  {
    const int row = t & 63;
    const int cb  = (t >> 6) * 32;
    const float gx = ggs[row * 4], gy = ggs[row * 4 + 1], gz = ggs[row * 4 + 2];
#pragma unroll
    for (int c = cb; c < cb + 32; c += 2) {
      const float h0 = pos_b1[c]     + gx * pos_w1[c]     + gy * pos_w1[128 + c]     + gz * pos_w1[256 + c];
      const float h1 = pos_b1[c + 1] + gx * pos_w1[c + 1] + gy * pos_w1[128 + c + 1] + gz * pos_w1[256 + c + 1];
      f16x2 pr; pr[0] = (f16)fmaxf(h0, 0.f); pr[1] = (f16)fmaxf(h1, 0.f);
      *(f16x2*)(qA + row * 128 + (c ^ ((row & 7) << 3))) = pr;
    }
  }
  __syncthreads();

  // ---- f0 = pos1 @ pos_w2^T + b2 + ga*attr_w + attr_b -> facc + fA ----
  f32x4 facc[4][2];   // persistent f: rows mt*16+lg*4+r, col n0+nt*16+l15
  {
    zacc(facc);
    gemm_tile(qA, wt, l15, lg, n0, facc);
#pragma unroll
    for (int nt = 0; nt < 2; ++nt) {
      const int col = n0 + nt * 16 + l15;
      const float bias = pos_b2[col] + attr_b[col];
      const float aw   = attr_w[col];
#pragma unroll
      for (int mt = 0; mt < 4; ++mt) {
#pragma unroll
        for (int r = 0; r < 4; ++r)
          facc[mt][nt][r] += bias + ggs[(mt * 16 + lg * 4 + r) * 4 + 3] * aw;
        stD(fA, mt * 16, n0 + nt * 16, l15, lg, facc[mt][nt]);
      }
    }
  }
  __syncthreads();

  // ---- 5 attention layers, 3 barriers each ----
  for (int l = 0; l < 5; ++l) {
    f16x4 vfrag[4][2];   // V B-frags (K=16), built in P1, consumed in P3
    {  // P1: G = f @ Mw -> qA (col-sliced); V = f @ Wv -> regs
      f32x4 acc[4][2];
      zacc(acc);
      gemm_tile(fA, wt + (7 + l) * 16384, l15, lg, n0, acc);
#pragma unroll
      for (int mt = 0; mt < 4; ++mt)
#pragma unroll
        for (int nt = 0; nt < 2; ++nt)
          stD(qA, mt * 16, n0 + nt * 16, l15, lg, acc[mt][nt]);
      zacc(acc);
      gemm_tile(fA, wt + (1 + l) * 16384, l15, lg, n0, acc);
#pragma unroll
      for (int mt = 0; mt < 4; ++mt)
#pragma unroll
        for (int nt = 0; nt < 2; ++nt)
#pragma unroll
        for (int r = 0; r < 4; ++r)
          vfrag[mt][nt][r] = (f16)acc[mt][nt][r];
    }
    __syncthreads();
    {  // P2: S = G_own @ f_own^T (K=32); softmax -> pAh (own target)
      f32x4 s = (f32x4){0.f, 0.f, 0.f, 0.f};
#pragma unroll
      for (int kc = 0; kc < 4; ++kc)
        s = MFMA16(ldA(qA, wv * 16, l15, lg, kc), ldA(fA, wv * 16, l15, lg, kc), s);
#pragma unroll
      for (int r = 0; r < 4; ++r) {
        float v = s[r] * 0.08838834764831844055f;   // 1/sqrt(128)
        float mx = v;
#pragma unroll
        for (int m = 1; m < 16; m <<= 1) mx = fmaxf(mx, __shfl_xor(mx, m));
        const float e = __expf(v - mx);
        float sm = e;
#pragma unroll
        for (int m = 1; m < 16; m <<= 1) sm += __shfl_xor(sm, m);
        // P[m=lg*4+r][k=l15] of target wv
        pAh[wv * 256 + (lg * 4 + r) * 16 + l15] = (f16)(e / sm);
      }
    }
    __syncthreads();
    {  // P3: PV (K=16): facc[tt][nt] += P_tt @ V_tt; stD fA (own cols)
#pragma unroll
      for (int tt = 0; tt < 4; ++tt) {
        // A-frag: m=l15, k=lg*4+j -> pAh[tt][l15][lg*4..+4]
        const f16x4 aP = *(const f16x4*)(pAh + tt * 256 + l15 * 16 + lg * 4);
#pragma unroll
        for (int nt = 0; nt < 2; ++nt) {
          facc[tt][nt] = MFMA16H(aP, vfrag[tt][nt], facc[tt][nt]);
          stD(fA, tt * 16, n0 + nt * 16, l15, lg, facc[tt][nt]);
        }
      }
    }
    __syncthreads();
  }

  // ---- feature head (epilogue overlays aux) ----
  float* feats = (float*)aux;          // [4][128] f32 (2048B)
  float* h1s   = feats + 512;          // [4][64]  (1024B)
  float* h2s   = h1s + 256;            // [4][16]  (256B)
  float* btmp  = h2s + 64;             // [4]
  {
    f32x4 acc[4][2];
    zacc(acc);
    gemm_tile(fA, wt + 6 * 16384, l15, lg, n0, acc);
#pragma unroll
    for (int nt = 0; nt < 2; ++nt) {
      const int col = n0 + nt * 16 + l15;
      const float bo = bout[col];
#pragma unroll
      for (int mt = 0; mt < 4; ++mt) {
        const f32x4 v = acc[mt][nt];
        float m = fmaxf(fmaxf(v[0], v[1]), fmaxf(v[2], v[3])) + bo;
        m = fmaxf(m, __shfl_xor(m, 16));
        m = fmaxf(m, __shfl_xor(m, 32));
        if (lg == 0) feats[mt * 128 + col] = m;
      }
    }
  }
  __syncthreads();
  {  // h1 = relu(feat @ ms_w1 + b1): 4 targets x 64
    const int tt = t >> 6, h = t & 63;
    float a = ms_b1[h];
#pragma unroll 4
    for (int c = 0; c < 128; ++c) a += feats[tt * 128 + c] * ms_w1[c * 64 + h];
    h1s[tt * 64 + h] = fmaxf(a, 0.f);
  }
  __syncthreads();
  if (t < 64) {
    const int tt = t >> 4, h = t & 15;
    float a = ms_b2[h];
#pragma unroll 4
    for (int c = 0; c < 64; ++c) a += h1s[tt * 64 + c] * ms_w2[c * 16 + h];
    h2s[tt * 16 + h] = fmaxf(a, 0.f);
  }
  __syncthreads();
  if (t < TPB) {
    float mu = ms_b3[0], lgs = ms_b3[1];
#pragma unroll
    for (int c = 0; c < 16; ++c) {
      mu  += h2s[t * 16 + c] * ms_w3[2 * c];
      lgs += h2s[t * 16 + c] * ms_w3[2 * c + 1];
    }
    const float sigma = expf(lgs);
    const float inv   = 1.f / (sigma * 1.41421356237309504880f);
    const float ta    = ((const float*)bx)[(WWIN + slot0 + t) * 4 + 3];
    const float p = 0.5f * (erff((ta + 0.5f - mu) * inv) - erff((ta - 0.5f - mu) * inv));
    float bits = -log2f(p + 1e-10f);
    btmp[t] = fminf(fmaxf(bits, 0.f), 50.f);
  }
  __syncthreads();
  if (t == 0) partials[blockIdx.x] = btmp[0] + btmp[1] + btmp[2] + btmp[3];
}

// ---------------------------------------------------------------------------
__global__ void reduce_kernel(const float* __restrict__ partials, float* __restrict__ out) {
  float s = 0.f;
  for (int i = threadIdx.x; i < NBLK; i += 256) s += partials[i];
#pragma unroll
  for (int m = 1; m < 64; m <<= 1) s += __shfl_xor(s, m);
  __shared__ float wsum[4];
  if ((threadIdx.x & 63) == 0) wsum[threadIdx.x >> 6] = s;
  __syncthreads();
  if (threadIdx.x == 0) out[0] = wsum[0] + wsum[1] + wsum[2] + wsum[3];
}

// ---------------------------------------------------------------------------
extern "C" void kernel_launch(void* const* d_in, const int* in_sizes, int n_in,
                              void* d_out, int out_size, void* d_ws, size_t ws_size,
                              hipStream_t stream) {
  const float4* bx     = (const float4*)d_in[0];
  const float* attr_w  = (const float*)d_in[1];
  const float* attr_b  = (const float*)d_in[2];
  const float* pos_w1  = (const float*)d_in[3];
  const float* pos_b1  = (const float*)d_in[4];
  const float* pos_w2  = (const float*)d_in[5];
  const float* pos_b2  = (const float*)d_in[6];
  const float* wq      = (const float*)d_in[7];
  const float* wk      = (const float*)d_in[8];
  const float* wv      = (const float*)d_in[9];
  const float* wout    = (const float*)d_in[10];
  const float* bout    = (const float*)d_in[11];
  const float* ms_w1   = (const float*)d_in[12];
  const float* ms_b1   = (const float*)d_in[13];
  const float* ms_w2   = (const float*)d_in[14];
  const float* ms_b2   = (const float*)d_in[15];
  const float* ms_w3   = (const float*)d_in[16];
  const float* ms_b3   = (const float*)d_in[17];

  f16*   wt       = (f16*)((char*)d_ws);                 // 384KB @ 0
  float* partials = (float*)((char*)d_ws + (1u << 19));  // 14KB  @ 512KB

  prep_kernel<<<(NMAT * 16384 + 255) / 256, 256, 0, stream>>>(pos_w2, wq, wk, wv, wout, wt);
  nn_kernel<<<NBLK, 256, 0, stream>>>(bx, wt, attr_w, attr_b,
                                      pos_w1, pos_b1, pos_b2, bout,
                                      ms_w1, ms_b1, ms_w2, ms_b2, ms_w3, ms_b3,
                                      partials);
  reduce_kernel<<<1, 256, 0, stream>>>(partials, (float*)d_out);
}